// Round 2
// baseline (947.436 us; speedup 1.0000x reference)
//
#include <hip/hip_runtime.h>
#include <hip/hip_bf16.h>

#define T_TOT 512
#define NB    128      // batch
#define NI    128      // n_inp
#define NH    1024     // n_hid
#define NJ    2048     // n_hid * n_ch

typedef __attribute__((ext_vector_type(8))) short short8;
typedef __attribute__((ext_vector_type(4))) float f32x4;

__device__ __forceinline__ short f2bf_s(float f) {
  __hip_bfloat16 h = __float2bfloat16(f);
  short s; __builtin_memcpy(&s, &h, 2); return s;
}
__device__ __forceinline__ unsigned short f2bf_u(float f) {
  __hip_bfloat16 h = __float2bfloat16(f);
  unsigned short s; __builtin_memcpy(&s, &h, 2); return s;
}
__device__ __forceinline__ float bf2f(unsigned short u) {
  unsigned v = ((unsigned)u) << 16; float f; __builtin_memcpy(&f, &v, 4); return f;
}
__device__ __forceinline__ float fast_tanh(float x) {
  float e = __expf(2.0f * x);
  return 1.0f - __fdividef(2.0f, e + 1.0f);   // exact at +-inf, abs err ~1e-7
}

// ---- kernel 1: split Wx_w (f32 [2048][128]) into hi/lo bf16 ----
__global__ void cvt_wx(const float* __restrict__ w,
                       unsigned short* __restrict__ hi,
                       unsigned short* __restrict__ lo) {
  int i = blockIdx.x * blockDim.x + threadIdx.x;
  for (int k = i; k < NJ * NI; k += gridDim.x * blockDim.x) {
    float f = w[k];
    unsigned short h = f2bf_u(f);
    hi[k] = h;
    lo[k] = f2bf_u(f - bf2f(h));
  }
}

// ---- kernel 2: U[m][j] = sum_i x[m][i] * W[j][i] + b[j] (fp32 out, split-bf16 MFMA) ----
// grid.x = T_c (one block per timestep = 128 rows), block = 256 (4 waves x 32 rows)
__global__ __launch_bounds__(256) void gemm_u(
    const float* __restrict__ x,            // chunk base, [T_c*128][128] f32
    const unsigned short* __restrict__ Whi, // [2048][128] bf16 (L2-resident)
    const unsigned short* __restrict__ Wlo, // [2048][128] bf16
    const float* __restrict__ Wxb,          // [2048]
    float* __restrict__ U)                  // [T_c*128][2048] f32
{
  const int w  = threadIdx.x >> 6;
  const int l  = threadIdx.x & 63;
  const int lr = l & 15;   // A-row / B-col within 16
  const int lk = l >> 4;   // k-group (8 contiguous k per lane)
  const long m0 = (long)blockIdx.x * 128 + w * 32;

  // A-panel (32 rows x K=128), split hi/lo, held in registers for the column sweep.
  // lane l holds A[l&15][(l>>4)*8 + e], e=0..7 per fragment.
  short8 ah[2][4], al[2][4];
  #pragma unroll
  for (int ms = 0; ms < 2; ++ms) {
    const float* xr = x + (m0 + ms * 16 + lr) * NI + lk * 8;
    #pragma unroll
    for (int kk = 0; kk < 4; ++kk) {
      float4 p = *(const float4*)(xr + kk * 32);
      float4 q = *(const float4*)(xr + kk * 32 + 4);
      float f[8] = {p.x, p.y, p.z, p.w, q.x, q.y, q.z, q.w};
      short8 vh, vl;
      #pragma unroll
      for (int e = 0; e < 8; ++e) {
        unsigned short h = f2bf_u(f[e]);
        vh[e] = (short)h;
        vl[e] = f2bf_s(f[e] - bf2f(h));
      }
      ah[ms][kk] = vh;
      al[ms][kk] = vl;
    }
  }

  for (int s = 0; s < NJ / 16; ++s) {
    const int j0 = s * 16;
    // B fragment: lane l holds B[(l>>4)*8+e][j0 + (l&15)] = W[j0+(l&15)][k] (contiguous)
    const size_t wo = (size_t)(j0 + lr) * NI + lk * 8;
    short8 bh[4], bl[4];
    #pragma unroll
    for (int kk = 0; kk < 4; ++kk) {
      bh[kk] = *(const short8*)(Whi + wo + kk * 32);
      bl[kk] = *(const short8*)(Wlo + wo + kk * 32);
    }
    f32x4 acc0 = {0.f, 0.f, 0.f, 0.f};
    f32x4 acc1 = {0.f, 0.f, 0.f, 0.f};
    #pragma unroll
    for (int kk = 0; kk < 4; ++kk) {
      acc0 = __builtin_amdgcn_mfma_f32_16x16x32_bf16(ah[0][kk], bh[kk], acc0, 0, 0, 0);
      acc0 = __builtin_amdgcn_mfma_f32_16x16x32_bf16(ah[0][kk], bl[kk], acc0, 0, 0, 0);
      acc0 = __builtin_amdgcn_mfma_f32_16x16x32_bf16(al[0][kk], bh[kk], acc0, 0, 0, 0);
      acc1 = __builtin_amdgcn_mfma_f32_16x16x32_bf16(ah[1][kk], bh[kk], acc1, 0, 0, 0);
      acc1 = __builtin_amdgcn_mfma_f32_16x16x32_bf16(ah[1][kk], bl[kk], acc1, 0, 0, 0);
      acc1 = __builtin_amdgcn_mfma_f32_16x16x32_bf16(al[1][kk], bh[kk], acc1, 0, 0, 0);
    }
    const float bias = Wxb[j0 + lr];
    // C/D layout: col = lane&15, row = (lane>>4)*4 + r  [m89]
    #pragma unroll
    for (int r = 0; r < 4; ++r) {
      const long row = m0 + lk * 4 + r;
      U[row * NJ + j0 + lr]        = acc0[r] + bias;
      U[(row + 16) * NJ + j0 + lr] = acc1[r] + bias;
    }
  }
}

// ---- kernel 3: sequential recurrence, one workgroup per batch element ----
__global__ __launch_bounds__(1024) void recur(
    const float* __restrict__ U,            // chunk [T_c][128][2048] f32, or nullptr (slow path)
    const float* __restrict__ x,            // full x (slow path only)
    const float* __restrict__ Wxw,          // f32 [2048][128] (slow path only)
    const float* __restrict__ Wxb,
    const float* __restrict__ Wyw,          // [2][2][1024][3]
    const float* __restrict__ Wyb,          // [2][1024]
    const float* __restrict__ Rw,           // [10][2048]
    const float* __restrict__ Rb,           // [10]
    float* __restrict__ state,              // [128][2048] carry between chunks
    float* __restrict__ out,                // [128][10]
    int T_c, int flags)                     // bit0 = first chunk, bit1 = last chunk
{
  const int b = blockIdx.x;
  const int n = threadIdx.x;
  __shared__ float2 h2[2][NH];              // double-buffered state {ch0, ch1}
  __shared__ float  xs[NI];                 // slow path x staging
  __shared__ float  red[16][10];            // projection reduce

  // thread-private local-conv weights: Wy_w[o][c][n][k]
  const float w000 = Wyw[(size_t)n*3+0],        w001 = Wyw[(size_t)n*3+1],        w002 = Wyw[(size_t)n*3+2];
  const float w010 = Wyw[(size_t)(NH+n)*3+0],   w011 = Wyw[(size_t)(NH+n)*3+1],   w012 = Wyw[(size_t)(NH+n)*3+2];
  const float w100 = Wyw[(size_t)(2*NH+n)*3+0], w101 = Wyw[(size_t)(2*NH+n)*3+1], w102 = Wyw[(size_t)(2*NH+n)*3+2];
  const float w110 = Wyw[(size_t)(3*NH+n)*3+0], w111 = Wyw[(size_t)(3*NH+n)*3+1], w112 = Wyw[(size_t)(3*NH+n)*3+2];
  const float bias0 = Wyb[n], bias1 = Wyb[NH + n];
  const int nm1 = (n + NH - 1) & (NH - 1);
  const int np1 = (n + 1) & (NH - 1);

  float c0, c1;   // own state, register-carried
  if (flags & 1) { c0 = 0.f; c1 = 0.f; }
  else { c0 = state[(size_t)b * NJ + n]; c1 = state[(size_t)b * NJ + NH + n]; }
  h2[0][n] = make_float2(c0, c1);
  __syncthreads();

  // circular window: h[(n+k-1) mod 1024], k=0..2 -> {nm1, n, np1}
#define STEP(CUR, U0, U1) do {                                                          \
    float2 Lv = h2[CUR][nm1];                                                           \
    float2 Rv = h2[CUR][np1];                                                           \
    float loc0 = bias0 + w000*Lv.x + w001*c0 + w002*Rv.x                                \
                       + w010*Lv.y + w011*c1 + w012*Rv.y;                               \
    float loc1 = bias1 + w100*Lv.x + w101*c0 + w102*Rv.x                                \
                       + w110*Lv.y + w111*c1 + w112*Rv.y;                               \
    c0 = fast_tanh((U0) + loc0);                                                        \
    c1 = fast_tanh((U1) + loc1);                                                        \
    h2[(CUR)^1][n] = make_float2(c0, c1);                                               \
    __syncthreads();                                                                    \
  } while (0)

  if (U) {
    const float* Ub = U + (size_t)b * NJ + n;
    // 2-deep prefetch, explicit slots (no runtime-indexed register arrays)
    float uA0 = Ub[0],               uA1 = Ub[NH];
    float uB0 = Ub[(size_t)NB * NJ], uB1 = Ub[(size_t)NB * NJ + NH];
    for (int t = 0; t < T_c; t += 2) {
      float u0 = uA0, u1 = uA1;
      if (t + 2 < T_c) { size_t o2 = (size_t)(t + 2) * NB * NJ; uA0 = Ub[o2]; uA1 = Ub[o2 + NH]; }
      STEP(0, u0, u1);
      u0 = uB0; u1 = uB1;
      if (t + 3 < T_c) { size_t o2 = (size_t)(t + 3) * NB * NJ; uB0 = Ub[o2]; uB1 = Ub[o2 + NH]; }
      STEP(1, u0, u1);
    }
  } else {
    // slow fallback: compute u inline (used only if ws_size is too small)
    for (int t = 0; t < T_c; t += 2) {
      #pragma unroll
      for (int half = 0; half < 2; ++half) {
        const int tt = t + half;
        if (n < NI) xs[n] = x[(size_t)tt * NB * NI + (size_t)b * NI + n];
        __syncthreads();
        float u0 = Wxb[n], u1 = Wxb[NH + n];
        const float* wr0 = Wxw + (size_t)n * NI;
        const float* wr1 = Wxw + (size_t)(NH + n) * NI;
        #pragma unroll 8
        for (int i = 0; i < NI; ++i) {
          u0 = fmaf(xs[i], wr0[i], u0);
          u1 = fmaf(xs[i], wr1[i], u1);
        }
        if (half == 0) STEP(0, u0, u1); else STEP(1, u0, u1);
      }
    }
  }
#undef STEP

  if (flags & 2) {
    // fused projection: out[b][r] = sum_j hy[b][j] * Rw[r][j] + Rb[r]
    float p[10];
    #pragma unroll
    for (int r = 0; r < 10; ++r)
      p[r] = c0 * Rw[(size_t)r * NJ + n] + c1 * Rw[(size_t)r * NJ + NH + n];
    #pragma unroll
    for (int r = 0; r < 10; ++r) {
      #pragma unroll
      for (int off = 32; off > 0; off >>= 1)
        p[r] += __shfl_down(p[r], off);
    }
    const int wv = n >> 6;
    if ((n & 63) == 0) {
      #pragma unroll
      for (int r = 0; r < 10; ++r) red[wv][r] = p[r];
    }
    __syncthreads();
    if (n < 10) {
      float s = 0.f;
      #pragma unroll
      for (int k = 0; k < 16; ++k) s += red[k][n];
      out[b * 10 + n] = s + Rb[n];
    }
  } else {
    state[(size_t)b * NJ + n]      = c0;
    state[(size_t)b * NJ + NH + n] = c1;
  }
}

extern "C" void kernel_launch(void* const* d_in, const int* in_sizes, int n_in,
                              void* d_out, int out_size, void* d_ws, size_t ws_size,
                              hipStream_t stream) {
  const float* x   = (const float*)d_in[0];
  const float* Wxw = (const float*)d_in[1];
  const float* Wxb = (const float*)d_in[2];
  const float* Wyw = (const float*)d_in[3];
  const float* Wyb = (const float*)d_in[4];
  const float* Rw  = (const float*)d_in[5];
  const float* Rb  = (const float*)d_in[6];
  float* out = (float*)d_out;

  const size_t w1_bytes = (size_t)NJ * NI * 2;       // 512 KB bf16 Wx (hi)
  const size_t wb_bytes = 2 * w1_bytes;              // hi + lo
  const size_t st_bytes = (size_t)NB * NJ * 4;       // 1 MB carry state
  const size_t ut_bytes = (size_t)NB * NJ * 4;       // 1 MB per timestep of U (fp32)
  unsigned short* Whi = (unsigned short*)d_ws;
  unsigned short* Wlo = (unsigned short*)((char*)d_ws + w1_bytes);
  float* state = (float*)((char*)d_ws + wb_bytes);
  float* U = (float*)((char*)d_ws + wb_bytes + st_bytes);

  long Tc = 0;
  if (ws_size > wb_bytes + st_bytes)
    Tc = (long)((ws_size - wb_bytes - st_bytes) / ut_bytes);
  if (Tc > T_TOT) Tc = T_TOT;
  Tc &= ~1L;   // keep chunks even (recur loop is unrolled by 2)

  if (Tc >= 2) {
    cvt_wx<<<64, 256, 0, stream>>>(Wxw, Whi, Wlo);
    for (int t0 = 0; t0 < T_TOT; t0 += (int)Tc) {
      int tc = (int)Tc; if (t0 + tc > T_TOT) tc = T_TOT - t0;
      gemm_u<<<dim3(tc), 256, 0, stream>>>(x + (size_t)t0 * NB * NI, Whi, Wlo, Wxb, U);
      const int flags = (t0 == 0 ? 1 : 0) | (t0 + tc >= T_TOT ? 2 : 0);
      recur<<<NB, 1024, 0, stream>>>(U, x, Wxw, Wxb, Wyw, Wyb, Rw, Rb, state, out, tc, flags);
    }
  } else {
    // workspace too small: fully fused slow path (correct, not fast)
    recur<<<NB, 1024, 0, stream>>>(nullptr, x, Wxw, Wxb, Wyw, Wyb, Rw, Rb, nullptr, out, T_TOT, 3);
  }
}

// Round 3
// 639.271 us; speedup vs baseline: 1.4821x; 1.4821x over previous
//
#include <hip/hip_runtime.h>
#include <hip/hip_bf16.h>

#define T_TOT 512
#define NB    128      // batch
#define NI    128      // n_inp
#define NH    1024     // n_hid
#define NJ    2048     // n_hid * n_ch

typedef __attribute__((ext_vector_type(8))) short short8;
typedef __attribute__((ext_vector_type(4))) float f32x4;

__device__ __forceinline__ short f2bf_s(float f) {
  __hip_bfloat16 h = __float2bfloat16(f);
  short s; __builtin_memcpy(&s, &h, 2); return s;
}
__device__ __forceinline__ unsigned short f2bf_u(float f) {
  __hip_bfloat16 h = __float2bfloat16(f);
  unsigned short s; __builtin_memcpy(&s, &h, 2); return s;
}
__device__ __forceinline__ float bf2f(unsigned short u) {
  unsigned v = ((unsigned)u) << 16; float f; __builtin_memcpy(&f, &v, 4); return f;
}
__device__ __forceinline__ float fast_tanh(float x) {
  float e = __expf(2.0f * x);
  return 1.0f - __fdividef(2.0f, e + 1.0f);   // exact at +-inf, abs err ~1e-7
}

// ---- kernel 1: split Wx_w (f32 [2048][128]) into hi/lo bf16 ----
__global__ void cvt_wx(const float* __restrict__ w,
                       unsigned short* __restrict__ hi,
                       unsigned short* __restrict__ lo) {
  int i = blockIdx.x * blockDim.x + threadIdx.x;
  for (int k = i; k < NJ * NI; k += gridDim.x * blockDim.x) {
    float f = w[k];
    unsigned short h = f2bf_u(f);
    hi[k] = h;
    lo[k] = f2bf_u(f - bf2f(h));
  }
}

#define MFMA __builtin_amdgcn_mfma_f32_16x16x32_bf16

// ---- kernel 2: U[m][j] = sum_i x[m][i]*W[j][i] + b[j] (fp32 out, split-bf16) ----
// grid = (T_c, 4): blockIdx.x = timestep (128 rows), blockIdx.y = 512-col quarter.
__global__ __launch_bounds__(256) void gemm_u(
    const float* __restrict__ x,            // chunk base, [T_c*128][128] f32
    const unsigned short* __restrict__ Whi, // [2048][128] bf16 (L2/L3-resident)
    const unsigned short* __restrict__ Wlo, // [2048][128] bf16
    const float* __restrict__ Wxb,          // [2048]
    float* __restrict__ U)                  // [T_c*128][2048] f32
{
  const int w  = threadIdx.x >> 6;
  const int l  = threadIdx.x & 63;
  const int lr = l & 15;   // A-row / B-col within 16
  const int lk = l >> 4;   // k-group (8 contiguous k per lane)
  const long m0 = (long)blockIdx.x * 128 + w * 32;
  const int jb = blockIdx.y * (NJ / 4);

  // A-panel (32 rows x K=128), split hi/lo, registers for the whole sweep.
  short8 ah[2][4], al[2][4];
  #pragma unroll
  for (int ms = 0; ms < 2; ++ms) {
    const float* xr = x + (m0 + ms * 16 + lr) * NI + lk * 8;
    #pragma unroll
    for (int kk = 0; kk < 4; ++kk) {
      float4 p = *(const float4*)(xr + kk * 32);
      float4 q = *(const float4*)(xr + kk * 32 + 4);
      float f[8] = {p.x, p.y, p.z, p.w, q.x, q.y, q.z, q.w};
      short8 vh, vl;
      #pragma unroll
      for (int e = 0; e < 8; ++e) {
        unsigned short h = f2bf_u(f[e]);
        vh[e] = (short)h;
        vl[e] = f2bf_s(f[e] - bf2f(h));
      }
      ah[ms][kk] = vh;
      al[ms][kk] = vl;
    }
  }

#define LOADB(BH, BL, J0) do {                                                \
    const size_t wo = (size_t)((J0) + lr) * NI + lk * 8;                      \
    BH[0] = *(const short8*)(Whi + wo);       BH[1] = *(const short8*)(Whi + wo + 32); \
    BH[2] = *(const short8*)(Whi + wo + 64);  BH[3] = *(const short8*)(Whi + wo + 96); \
    BL[0] = *(const short8*)(Wlo + wo);       BL[1] = *(const short8*)(Wlo + wo + 32); \
    BL[2] = *(const short8*)(Wlo + wo + 64);  BL[3] = *(const short8*)(Wlo + wo + 96); \
  } while (0)

#define COMPUTE(BH, BL, J0) do {                                              \
    f32x4 acc0 = {0.f, 0.f, 0.f, 0.f};                                        \
    f32x4 acc1 = {0.f, 0.f, 0.f, 0.f};                                        \
    _Pragma("unroll")                                                         \
    for (int kk = 0; kk < 4; ++kk) {                                          \
      acc0 = MFMA(ah[0][kk], BH[kk], acc0, 0, 0, 0);                          \
      acc0 = MFMA(ah[0][kk], BL[kk], acc0, 0, 0, 0);                          \
      acc0 = MFMA(al[0][kk], BH[kk], acc0, 0, 0, 0);                          \
      acc1 = MFMA(ah[1][kk], BH[kk], acc1, 0, 0, 0);                          \
      acc1 = MFMA(ah[1][kk], BL[kk], acc1, 0, 0, 0);                          \
      acc1 = MFMA(al[1][kk], BH[kk], acc1, 0, 0, 0);                          \
    }                                                                         \
    const float bias = Wxb[(J0) + lr];                                        \
    _Pragma("unroll")                                                         \
    for (int r = 0; r < 4; ++r) {                                             \
      const long row = m0 + lk * 4 + r;                                       \
      U[row * NJ + (J0) + lr]        = acc0[r] + bias;                        \
      U[(row + 16) * NJ + (J0) + lr] = acc1[r] + bias;                        \
    }                                                                         \
  } while (0)

  short8 bhA[4], blA[4], bhB[4], blB[4];
  LOADB(bhA, blA, jb);
  for (int s = 0; s < 32; s += 2) {
    const int j0 = jb + s * 16;
    LOADB(bhB, blB, j0 + 16);                 // prefetch strip s+1
    COMPUTE(bhA, blA, j0);
    if (s + 2 < 32) LOADB(bhA, blA, j0 + 32); // prefetch strip s+2
    COMPUTE(bhB, blB, j0 + 16);
  }
#undef LOADB
#undef COMPUTE
}

// ---- kernel 3: recurrence. 256 threads/block, 4 hidden indices per thread ----
__global__ __launch_bounds__(256) void recur(
    const float* __restrict__ U,            // chunk [T_c][128][2048] f32
    const float* __restrict__ Wyw,          // [2][2][1024][3]
    const float* __restrict__ Wyb,          // [2][1024]
    const float* __restrict__ Rw,           // [10][2048]
    const float* __restrict__ Rb,           // [10]
    float* __restrict__ state,              // [128][2048] carry between chunks
    float* __restrict__ out,                // [128][10]
    int T_c, int flags)                     // bit0 = first chunk, bit1 = last chunk
{
  const int b  = blockIdx.x;
  const int tid = threadIdx.x;
  const int n0 = tid * 4;
  __shared__ float2 h2[2][NH];              // {ch0, ch1} per hidden idx, double-buffered
  __shared__ float  red[4][10];

  // conv weights (registers, constant-indexed after unroll): W[o][c][m][k]
  float W00[12], W01[12], W10[12], W11[12];
  {
    const size_t o00 = (size_t)n0 * 3;
    const size_t o01 = (size_t)(NH + n0) * 3;
    const size_t o10 = (size_t)(2 * NH + n0) * 3;
    const size_t o11 = (size_t)(3 * NH + n0) * 3;
    *(float4*)&W00[0] = *(const float4*)(Wyw + o00);
    *(float4*)&W00[4] = *(const float4*)(Wyw + o00 + 4);
    *(float4*)&W00[8] = *(const float4*)(Wyw + o00 + 8);
    *(float4*)&W01[0] = *(const float4*)(Wyw + o01);
    *(float4*)&W01[4] = *(const float4*)(Wyw + o01 + 4);
    *(float4*)&W01[8] = *(const float4*)(Wyw + o01 + 8);
    *(float4*)&W10[0] = *(const float4*)(Wyw + o10);
    *(float4*)&W10[4] = *(const float4*)(Wyw + o10 + 4);
    *(float4*)&W10[8] = *(const float4*)(Wyw + o10 + 8);
    *(float4*)&W11[0] = *(const float4*)(Wyw + o11);
    *(float4*)&W11[4] = *(const float4*)(Wyw + o11 + 4);
    *(float4*)&W11[8] = *(const float4*)(Wyw + o11 + 8);
  }
  const float4 B0 = *(const float4*)(Wyb + n0);
  const float4 B1 = *(const float4*)(Wyb + NH + n0);
  const float B0a[4] = {B0.x, B0.y, B0.z, B0.w};
  const float B1a[4] = {B1.x, B1.y, B1.z, B1.w};
  const int nm1 = (n0 + NH - 1) & (NH - 1);
  const int np4 = (n0 + 4) & (NH - 1);

  float y0[4], y1[4];   // own state (ch0, ch1), register-carried
  if (flags & 1) {
    #pragma unroll
    for (int j = 0; j < 4; ++j) { y0[j] = 0.f; y1[j] = 0.f; }
  } else {
    float4 s0 = *(const float4*)(state + (size_t)b * NJ + n0);
    float4 s1 = *(const float4*)(state + (size_t)b * NJ + NH + n0);
    y0[0]=s0.x; y0[1]=s0.y; y0[2]=s0.z; y0[3]=s0.w;
    y1[0]=s1.x; y1[1]=s1.y; y1[2]=s1.z; y1[3]=s1.w;
  }
  *(float4*)(&h2[0][n0])     = make_float4(y0[0], y1[0], y0[1], y1[1]);
  *(float4*)(&h2[0][n0 + 2]) = make_float4(y0[2], y1[2], y0[3], y1[3]);
  __syncthreads();

#define STEP(CUR, U0V, U1V) do {                                              \
    const float2 Lv = h2[CUR][nm1];                                           \
    const float2 Rv = h2[CUR][np4];                                           \
    float h0[6], h1[6];                                                       \
    h0[0]=Lv.x; h0[1]=y0[0]; h0[2]=y0[1]; h0[3]=y0[2]; h0[4]=y0[3]; h0[5]=Rv.x; \
    h1[0]=Lv.y; h1[1]=y1[0]; h1[2]=y1[1]; h1[3]=y1[2]; h1[4]=y1[3]; h1[5]=Rv.y; \
    const float u0a[4] = {U0V.x, U0V.y, U0V.z, U0V.w};                        \
    const float u1a[4] = {U1V.x, U1V.y, U1V.z, U1V.w};                        \
    _Pragma("unroll")                                                         \
    for (int j = 0; j < 4; ++j) {                                             \
      float loc0 = B0a[j] + W00[j*3]*h0[j] + W00[j*3+1]*h0[j+1] + W00[j*3+2]*h0[j+2] \
                          + W01[j*3]*h1[j] + W01[j*3+1]*h1[j+1] + W01[j*3+2]*h1[j+2]; \
      float loc1 = B1a[j] + W10[j*3]*h0[j] + W10[j*3+1]*h0[j+1] + W10[j*3+2]*h0[j+2] \
                          + W11[j*3]*h1[j] + W11[j*3+1]*h1[j+1] + W11[j*3+2]*h1[j+2]; \
      y0[j] = fast_tanh(u0a[j] + loc0);                                       \
      y1[j] = fast_tanh(u1a[j] + loc1);                                       \
    }                                                                         \
    *(float4*)(&h2[(CUR)^1][n0])     = make_float4(y0[0], y1[0], y0[1], y1[1]); \
    *(float4*)(&h2[(CUR)^1][n0 + 2]) = make_float4(y0[2], y1[2], y0[3], y1[3]); \
    __syncthreads();                                                          \
  } while (0)

  const float* Ub = U + (size_t)b * NJ + n0;
  // 4-deep explicit prefetch (T_c is a multiple of 4)
  float4 uA0 = *(const float4*)(Ub);
  float4 uA1 = *(const float4*)(Ub + NH);
  float4 uB0 = *(const float4*)(Ub + (size_t)1 * NB * NJ);
  float4 uB1 = *(const float4*)(Ub + (size_t)1 * NB * NJ + NH);
  float4 uC0 = *(const float4*)(Ub + (size_t)2 * NB * NJ);
  float4 uC1 = *(const float4*)(Ub + (size_t)2 * NB * NJ + NH);
  float4 uD0 = *(const float4*)(Ub + (size_t)3 * NB * NJ);
  float4 uD1 = *(const float4*)(Ub + (size_t)3 * NB * NJ + NH);

  for (int t = 0; t < T_c; t += 4) {
    float4 v0 = uA0, v1 = uA1;
    if (t + 4 < T_c) { const size_t o = (size_t)(t + 4) * NB * NJ; uA0 = *(const float4*)(Ub + o); uA1 = *(const float4*)(Ub + o + NH); }
    STEP(0, v0, v1);
    v0 = uB0; v1 = uB1;
    if (t + 5 < T_c) { const size_t o = (size_t)(t + 5) * NB * NJ; uB0 = *(const float4*)(Ub + o); uB1 = *(const float4*)(Ub + o + NH); }
    STEP(1, v0, v1);
    v0 = uC0; v1 = uC1;
    if (t + 6 < T_c) { const size_t o = (size_t)(t + 6) * NB * NJ; uC0 = *(const float4*)(Ub + o); uC1 = *(const float4*)(Ub + o + NH); }
    STEP(0, v0, v1);
    v0 = uD0; v1 = uD1;
    if (t + 7 < T_c) { const size_t o = (size_t)(t + 7) * NB * NJ; uD0 = *(const float4*)(Ub + o); uD1 = *(const float4*)(Ub + o + NH); }
    STEP(1, v0, v1);
  }
#undef STEP

  if (flags & 2) {
    // out[b][r] = sum_j hy[b][j] * Rw[r][j] + Rb[r]
    float p[10];
    #pragma unroll
    for (int r = 0; r < 10; ++r) {
      float4 ra = *(const float4*)(Rw + (size_t)r * NJ + n0);
      float4 rb = *(const float4*)(Rw + (size_t)r * NJ + NH + n0);
      p[r] = y0[0]*ra.x + y0[1]*ra.y + y0[2]*ra.z + y0[3]*ra.w
           + y1[0]*rb.x + y1[1]*rb.y + y1[2]*rb.z + y1[3]*rb.w;
    }
    #pragma unroll
    for (int r = 0; r < 10; ++r) {
      #pragma unroll
      for (int off = 32; off > 0; off >>= 1)
        p[r] += __shfl_down(p[r], off);
    }
    const int wv = tid >> 6;
    if ((tid & 63) == 0) {
      #pragma unroll
      for (int r = 0; r < 10; ++r) red[wv][r] = p[r];
    }
    __syncthreads();
    if (tid < 10) {
      out[b * 10 + tid] = red[0][tid] + red[1][tid] + red[2][tid] + red[3][tid] + Rb[tid];
    }
  } else {
    *(float4*)(state + (size_t)b * NJ + n0)      = make_float4(y0[0], y0[1], y0[2], y0[3]);
    *(float4*)(state + (size_t)b * NJ + NH + n0) = make_float4(y1[0], y1[1], y1[2], y1[3]);
  }
}

// ---- fallback (only if ws_size is tiny): fully fused slow path ----
__global__ __launch_bounds__(1024) void recur_fb(
    const float* __restrict__ x,
    const float* __restrict__ Wxw, const float* __restrict__ Wxb,
    const float* __restrict__ Wyw, const float* __restrict__ Wyb,
    const float* __restrict__ Rw,  const float* __restrict__ Rb,
    float* __restrict__ out)
{
  const int b = blockIdx.x;
  const int n = threadIdx.x;
  __shared__ float2 h2[2][NH];
  __shared__ float  xs[NI];
  __shared__ float  red[16][10];

  const float w000 = Wyw[(size_t)n*3+0],        w001 = Wyw[(size_t)n*3+1],        w002 = Wyw[(size_t)n*3+2];
  const float w010 = Wyw[(size_t)(NH+n)*3+0],   w011 = Wyw[(size_t)(NH+n)*3+1],   w012 = Wyw[(size_t)(NH+n)*3+2];
  const float w100 = Wyw[(size_t)(2*NH+n)*3+0], w101 = Wyw[(size_t)(2*NH+n)*3+1], w102 = Wyw[(size_t)(2*NH+n)*3+2];
  const float w110 = Wyw[(size_t)(3*NH+n)*3+0], w111 = Wyw[(size_t)(3*NH+n)*3+1], w112 = Wyw[(size_t)(3*NH+n)*3+2];
  const float bias0 = Wyb[n], bias1 = Wyb[NH + n];
  const int nm1 = (n + NH - 1) & (NH - 1);
  const int np1 = (n + 1) & (NH - 1);

  float c0 = 0.f, c1 = 0.f;
  h2[0][n] = make_float2(c0, c1);
  __syncthreads();

  int cur = 0;
  for (int t = 0; t < T_TOT; ++t) {
    if (n < NI) xs[n] = x[(size_t)t * NB * NI + (size_t)b * NI + n];
    __syncthreads();
    float u0 = Wxb[n], u1 = Wxb[NH + n];
    const float* wr0 = Wxw + (size_t)n * NI;
    const float* wr1 = Wxw + (size_t)(NH + n) * NI;
    #pragma unroll 8
    for (int i = 0; i < NI; ++i) {
      u0 = fmaf(xs[i], wr0[i], u0);
      u1 = fmaf(xs[i], wr1[i], u1);
    }
    float2 Lv = h2[cur][nm1];
    float2 Rv = h2[cur][np1];
    float loc0 = bias0 + w000*Lv.x + w001*c0 + w002*Rv.x + w010*Lv.y + w011*c1 + w012*Rv.y;
    float loc1 = bias1 + w100*Lv.x + w101*c0 + w102*Rv.x + w110*Lv.y + w111*c1 + w112*Rv.y;
    c0 = fast_tanh(u0 + loc0);
    c1 = fast_tanh(u1 + loc1);
    h2[cur ^ 1][n] = make_float2(c0, c1);
    cur ^= 1;
    __syncthreads();
  }

  float p[10];
  #pragma unroll
  for (int r = 0; r < 10; ++r)
    p[r] = c0 * Rw[(size_t)r * NJ + n] + c1 * Rw[(size_t)r * NJ + NH + n];
  #pragma unroll
  for (int r = 0; r < 10; ++r) {
    #pragma unroll
    for (int off = 32; off > 0; off >>= 1)
      p[r] += __shfl_down(p[r], off);
  }
  const int wv = n >> 6;
  if ((n & 63) == 0) {
    #pragma unroll
    for (int r = 0; r < 10; ++r) red[wv][r] = p[r];
  }
  __syncthreads();
  if (n < 10) {
    float s = 0.f;
    #pragma unroll
    for (int k = 0; k < 16; ++k) s += red[k][n];
    out[b * 10 + n] = s + Rb[n];
  }
}

extern "C" void kernel_launch(void* const* d_in, const int* in_sizes, int n_in,
                              void* d_out, int out_size, void* d_ws, size_t ws_size,
                              hipStream_t stream) {
  const float* x   = (const float*)d_in[0];
  const float* Wxw = (const float*)d_in[1];
  const float* Wxb = (const float*)d_in[2];
  const float* Wyw = (const float*)d_in[3];
  const float* Wyb = (const float*)d_in[4];
  const float* Rw  = (const float*)d_in[5];
  const float* Rb  = (const float*)d_in[6];
  float* out = (float*)d_out;

  const size_t w1_bytes = (size_t)NJ * NI * 2;       // 512 KB bf16 Wx (hi)
  const size_t wb_bytes = 2 * w1_bytes;              // hi + lo
  const size_t st_bytes = (size_t)NB * NJ * 4;       // 1 MB carry state
  const size_t ut_bytes = (size_t)NB * NJ * 4;       // 1 MB per timestep of U (fp32)
  unsigned short* Whi = (unsigned short*)d_ws;
  unsigned short* Wlo = (unsigned short*)((char*)d_ws + w1_bytes);
  float* state = (float*)((char*)d_ws + wb_bytes);
  float* U = (float*)((char*)d_ws + wb_bytes + st_bytes);

  long Tc = 0;
  if (ws_size > wb_bytes + st_bytes)
    Tc = (long)((ws_size - wb_bytes - st_bytes) / ut_bytes);
  if (Tc > T_TOT) Tc = T_TOT;
  Tc &= ~3L;   // chunks multiple of 4 (recur unroll/prefetch depth)

  if (Tc >= 4) {
    cvt_wx<<<64, 256, 0, stream>>>(Wxw, Whi, Wlo);
    for (int t0 = 0; t0 < T_TOT; t0 += (int)Tc) {
      int tc = (int)Tc; if (t0 + tc > T_TOT) tc = T_TOT - t0;
      gemm_u<<<dim3(tc, 4), 256, 0, stream>>>(x + (size_t)t0 * NB * NI, Whi, Wlo, Wxb, U);
      const int flags = (t0 == 0 ? 1 : 0) | (t0 + tc >= T_TOT ? 2 : 0);
      recur<<<NB, 256, 0, stream>>>(U, Wyw, Wyb, Rw, Rb, state, out, tc, flags);
    }
  } else {
    recur_fb<<<NB, 1024, 0, stream>>>(x, Wxw, Wxb, Wyw, Wyb, Rw, Rb, out);
  }
}